// Round 1
// baseline (5366.306 us; speedup 1.0000x reference)
//
#include <hip/hip_runtime.h>
#include <math.h>

#define B 128
#define T 128
#define H 256
#define E 300
#define HD4 1024   // 4*H
#define D2H 512    // 2*H

__device__ __forceinline__ float sigm(float x) { return 1.0f / (1.0f + expf(-x)); }

// ---------------- embedding gather ----------------
__global__ void k_embed(const int* __restrict__ ids, const float* __restrict__ tab,
                        float* __restrict__ emb) {
    int i = blockIdx.x * blockDim.x + threadIdx.x;
    const int total = B * T * E;
    if (i >= total) return;
    int row = i / E, col = i - row * E;
    emb[i] = tab[(size_t)ids[row] * E + col];
}

// ---------------- Whh transpose: WT[k][j] = W[j][k], W is (1024,256) ----------------
__global__ void k_transpose(const float* __restrict__ W, float* __restrict__ WT) {
    int i = blockIdx.x * blockDim.x + threadIdx.x;  // over 1024*256
    if (i >= HD4 * H) return;
    int r = i >> 8;          // row in W (0..1023)
    int c = i & 255;         // col in W (0..255)
    WT[c * HD4 + r] = W[i];
}

// ---------------- fp32 GEMM: out[(t*B+b)*1024 + n] = A[m]·W[n] + bias[n], m=b*T+t ----
__global__ __launch_bounds__(256) void k_gemm_xg(const float* __restrict__ A, int K,
                                                 const float* __restrict__ W,
                                                 const float* __restrict__ bias,
                                                 float* __restrict__ out) {
    __shared__ float As[16][68];
    __shared__ float Bs[16][68];
    const int n0 = blockIdx.x * 64;
    const int m0 = blockIdx.y * 64;
    const int tid = threadIdx.x;
    const int lk = tid & 15;
    const int li = tid >> 4;
    const int tm = (tid & 15) << 2;
    const int tn = (tid >> 4) << 2;
    float acc[4][4] = {};
    for (int k0 = 0; k0 < K; k0 += 16) {
        int k = k0 + lk;
        bool kv = (k < K);
#pragma unroll
        for (int j = 0; j < 4; ++j) {
            As[lk][li + 16 * j] = kv ? A[(size_t)(m0 + li + 16 * j) * K + k] : 0.0f;
            Bs[lk][li + 16 * j] = kv ? W[(size_t)(n0 + li + 16 * j) * K + k] : 0.0f;
        }
        __syncthreads();
#pragma unroll
        for (int kk = 0; kk < 16; ++kk) {
            float a[4], b[4];
#pragma unroll
            for (int i = 0; i < 4; ++i) a[i] = As[kk][tm + i];
#pragma unroll
            for (int j = 0; j < 4; ++j) b[j] = Bs[kk][tn + j];
#pragma unroll
            for (int i = 0; i < 4; ++i)
#pragma unroll
                for (int j = 0; j < 4; ++j) acc[i][j] += a[i] * b[j];
        }
        __syncthreads();
    }
#pragma unroll
    for (int i = 0; i < 4; ++i) {
        int m = m0 + tm + i;
        int bb = m >> 7;     // m / T
        int tt = m & 127;    // m % T
        float* orow = out + ((size_t)(tt * B + bb)) * HD4 + n0 + tn;
#pragma unroll
        for (int j = 0; j < 4; ++j) orow[j] = acc[i][j] + bias[n0 + tn + j];
    }
}

// ---------------- init h/c from h0/c0 (layout (2,B,H) matches) ----------------
__global__ void k_init_hc(const float* __restrict__ h0, const float* __restrict__ c0,
                          float* __restrict__ h_buf, float* __restrict__ c_buf) {
    int i = blockIdx.x * blockDim.x + threadIdx.x;
    if (i < 2 * B * H) {
        h_buf[i] = h0[i];
        c_buf[i] = c0[i];
    }
}

// ---------------- one LSTM timestep, both directions ----------------
// grid (4, 32, 2), block 256. xg layout: [t][b][1024]. h/c layout: [dir][b][u].
__global__ __launch_bounds__(256) void k_lstm_step(
    const float* __restrict__ xg_f, const float* __restrict__ xg_r,
    const float* __restrict__ WT_f, const float* __restrict__ WT_r,
    const float* __restrict__ h_in, float* __restrict__ h_out,
    float* __restrict__ c_buf, float* __restrict__ o, int s) {
    const int d = blockIdx.z;
    const int t = d ? (T - 1 - s) : s;
    const float* xg = d ? xg_r : xg_f;
    const float* WT = d ? WT_r : WT_f;
    const int u = blockIdx.x * 64 + (threadIdx.x & 63);
    const int bl = threadIdx.x >> 6;  // 0..3
    const int b = blockIdx.y * 4 + bl;

    __shared__ float hsm[4][H];
    for (int i = threadIdx.x; i < 4 * H; i += 256) {
        hsm[i >> 8][i & 255] = h_in[(d * B + blockIdx.y * 4 + (i >> 8)) * H + (i & 255)];
    }
    __syncthreads();

    float a0 = 0.f, a1 = 0.f, a2 = 0.f, a3 = 0.f;
    const float* wp = WT + u;
#pragma unroll 8
    for (int k = 0; k < H; ++k) {
        float hv = hsm[bl][k];
        a0 += hv * wp[k * HD4 + 0 * H];
        a1 += hv * wp[k * HD4 + 1 * H];
        a2 += hv * wp[k * HD4 + 2 * H];
        a3 += hv * wp[k * HD4 + 3 * H];
    }
    const float* xr = xg + ((size_t)t * B + b) * HD4;
    float gi = xr[u] + a0;
    float gf = xr[H + u] + a1;
    float gg = xr[2 * H + u] + a2;
    float go = xr[3 * H + u] + a3;
    int hc = (d * B + b) * H + u;
    float cn = sigm(gf) * c_buf[hc] + sigm(gi) * tanhf(gg);
    float hn = sigm(go) * tanhf(cn);
    c_buf[hc] = cn;
    h_out[hc] = hn;
    o[((size_t)b * T + t) * D2H + d * H + u] = hn;
}

// ---------------- gt = sigmoid(o1 · gt_W + gt_b), one wave per row ----------------
__global__ __launch_bounds__(256) void k_gt(const float* __restrict__ o1,
                                            const float* __restrict__ gtW,
                                            const float* __restrict__ gtb,
                                            float* __restrict__ gt) {
    int row = blockIdx.x * 4 + (threadIdx.x >> 6);
    int lane = threadIdx.x & 63;
    const float* x = o1 + (size_t)row * D2H;
    float p = 0.f;
    for (int j = lane; j < D2H; j += 64) p += x[j] * gtW[j];
#pragma unroll
    for (int off = 32; off; off >>= 1) p += __shfl_down(p, off);
    if (lane == 0) gt[row] = sigm(p + gtb[0]);
}

// ---------------- gated temporal scan: hs2 ----------------
__global__ void k_scan(const float* __restrict__ o2, const float* __restrict__ gt,
                       float* __restrict__ hs2) {
    int b = blockIdx.x >> 1;
    int f = ((blockIdx.x & 1) << 8) + threadIdx.x;
    const float* src = o2 + (size_t)b * T * D2H + f;
    float* dst = hs2 + (size_t)b * T * D2H + f;
    float prev = src[0];
    dst[0] = prev;
    for (int t = 1; t < T; ++t) {
        float g = gt[b * T + t];
        prev = g * src[(size_t)t * D2H] + (1.0f - g) * prev;
        dst[(size_t)t * D2H] = prev;
    }
}

// ---------------- classifiers + softmax + NLL + argmax ----------------
__global__ __launch_bounds__(256) void k_cls(
    const float* __restrict__ o1, const float* __restrict__ hs2,
    const float* __restrict__ c1W, const float* __restrict__ c1b,
    const float* __restrict__ c2W, const float* __restrict__ c2b,
    const float* __restrict__ c3W, const float* __restrict__ c3b,
    const float* __restrict__ trans, const float* __restrict__ y_op,
    const float* __restrict__ y_bd, const float* __restrict__ y_oe,
    float* __restrict__ out_pred, float* __restrict__ out_loss) {
    int row = blockIdx.x * 4 + (threadIdx.x >> 6);
    int lane = threadIdx.x & 63;
    const float* x1 = o1 + (size_t)row * D2H;
    const float* x2 = hs2 + (size_t)row * D2H;
    float p1[5] = {}, p2[13] = {}, p3[2] = {};
    for (int j = lane; j < D2H; j += 64) {
        float a = x1[j], h = x2[j];
#pragma unroll
        for (int c = 0; c < 5; ++c) p1[c] += a * c1W[c * D2H + j];
#pragma unroll
        for (int c = 0; c < 13; ++c) p2[c] += h * c2W[c * D2H + j];
#pragma unroll
        for (int c = 0; c < 2; ++c) p3[c] += a * c3W[c * D2H + j];
    }
#pragma unroll
    for (int c = 0; c < 5; ++c)
#pragma unroll
        for (int off = 32; off; off >>= 1) p1[c] += __shfl_down(p1[c], off);
#pragma unroll
    for (int c = 0; c < 13; ++c)
#pragma unroll
        for (int off = 32; off; off >>= 1) p2[c] += __shfl_down(p2[c], off);
#pragma unroll
    for (int c = 0; c < 2; ++c)
#pragma unroll
        for (int off = 32; off; off >>= 1) p3[c] += __shfl_down(p3[c], off);

    if (lane == 0) {
        float z1[5], z2[13], z3[2];
        float m = -1e30f, s;
        for (int c = 0; c < 5; ++c) { z1[c] = p1[c] + c1b[c]; m = fmaxf(m, z1[c]); }
        s = 0.f;
        for (int c = 0; c < 5; ++c) { z1[c] = expf(z1[c] - m); s += z1[c]; }
        for (int c = 0; c < 5; ++c) z1[c] /= s;          // szt
        m = -1e30f;
        for (int c = 0; c < 13; ++c) { z2[c] = p2[c] + c2b[c]; m = fmaxf(m, z2[c]); }
        s = 0.f;
        for (int c = 0; c < 13; ++c) { z2[c] = expf(z2[c] - m); s += z2[c]; }
        for (int c = 0; c < 13; ++c) z2[c] /= s;         // szs
        m = fmaxf(p3[0] + c3b[0], p3[1] + c3b[1]);
        z3[0] = expf(p3[0] + c3b[0] - m);
        z3[1] = expf(p3[1] + c3b[1] - m);
        s = z3[0] + z3[1];
        z3[0] /= s; z3[1] /= s;                          // soe

        float at = 0.f;
        for (int c = 0; c < 5; ++c) at += z1[c] * z1[c];
        at *= 0.5f;

        float lsum = 0.f;
        float best = -1e30f;
        int arg = 0;
        for (int c = 0; c < 13; ++c) {
            float s2v = 0.f;
            for (int j = 0; j < 5; ++j) s2v += z1[j] * trans[j * 13 + c];
            float v = at * s2v + (1.0f - at) * z2[c];
            lsum += y_op[(size_t)row * 13 + c] * logf(v);
            if (v > best) { best = v; arg = c; }
        }
        for (int j = 0; j < 5; ++j) lsum += y_bd[(size_t)row * 5 + j] * logf(z1[j]);
        for (int k = 0; k < 2; ++k) lsum += y_oe[(size_t)row * 2 + k] * logf(z3[k]);
        atomicAdd(out_loss, -lsum * (1.0f / T));
        out_pred[row] = (float)arg;
    }
}

extern "C" void kernel_launch(void* const* d_in, const int* in_sizes, int n_in,
                              void* d_out, int out_size, void* d_ws, size_t ws_size,
                              hipStream_t stream) {
    const int* ids = (const int*)d_in[0];
    const float* y_op = (const float*)d_in[1];
    const float* y_bd = (const float*)d_in[2];
    const float* y_oe = (const float*)d_in[3];
    const float* tab = (const float*)d_in[4];
    const float* trans = (const float*)d_in[5];
    const float* l1_Wih_f = (const float*)d_in[6];
    const float* l1_Whh_f = (const float*)d_in[7];
    const float* l1_b_f = (const float*)d_in[8];
    const float* l1_Wih_r = (const float*)d_in[9];
    const float* l1_Whh_r = (const float*)d_in[10];
    const float* l1_b_r = (const float*)d_in[11];
    const float* l2_Wih_f = (const float*)d_in[12];
    const float* l2_Whh_f = (const float*)d_in[13];
    const float* l2_b_f = (const float*)d_in[14];
    const float* l2_Wih_r = (const float*)d_in[15];
    const float* l2_Whh_r = (const float*)d_in[16];
    const float* l2_b_r = (const float*)d_in[17];
    const float* gtW = (const float*)d_in[18];
    const float* gtb = (const float*)d_in[19];
    const float* c1W = (const float*)d_in[20];
    const float* c1b = (const float*)d_in[21];
    const float* c2W = (const float*)d_in[22];
    const float* c2b = (const float*)d_in[23];
    const float* c3W = (const float*)d_in[24];
    const float* c3b = (const float*)d_in[25];
    const float* h01 = (const float*)d_in[26];
    const float* c01 = (const float*)d_in[27];
    const float* h02 = (const float*)d_in[28];
    const float* c02 = (const float*)d_in[29];

    float* ws = (float*)d_ws;
    float* emb = ws;                          // 4,915,200
    float* xg_f = emb + 4915200;              // 16,777,216
    float* xg_r = xg_f + 16777216;            // 16,777,216
    float* o1 = xg_r + 16777216;              // 8,388,608
    float* o2 = o1 + 8388608;                 // 8,388,608
    float* hs2 = o2 + 8388608;                // 8,388,608
    float* wt = hs2 + 8388608;                // 4 * 262,144
    float* wt_l1f = wt;
    float* wt_l1r = wt + 262144;
    float* wt_l2f = wt + 524288;
    float* wt_l2r = wt + 786432;
    float* h_buf = wt + 1048576;              // 2 * 65,536 (ping-pong)
    float* c_buf = h_buf + 131072;            // 65,536
    float* gt = c_buf + 65536;                // 16,384

    float* out_pred = (float*)d_out;
    float* out_loss = out_pred + B * T;

    // zero the loss accumulator (harness does not re-poison between replays)
    hipMemsetAsync(out_loss, 0, sizeof(float), stream);

    // embedding gather
    k_embed<<<(B * T * E + 255) / 256, 256, 0, stream>>>(ids, tab, emb);

    // Whh transposes
    k_transpose<<<(HD4 * H + 255) / 256, 256, 0, stream>>>(l1_Whh_f, wt_l1f);
    k_transpose<<<(HD4 * H + 255) / 256, 256, 0, stream>>>(l1_Whh_r, wt_l1r);
    k_transpose<<<(HD4 * H + 255) / 256, 256, 0, stream>>>(l2_Whh_f, wt_l2f);
    k_transpose<<<(HD4 * H + 255) / 256, 256, 0, stream>>>(l2_Whh_r, wt_l2r);

    dim3 ggrid(HD4 / 64, (B * T) / 64);

    // layer 1 xg
    k_gemm_xg<<<ggrid, 256, 0, stream>>>(emb, E, l1_Wih_f, l1_b_f, xg_f);
    k_gemm_xg<<<ggrid, 256, 0, stream>>>(emb, E, l1_Wih_r, l1_b_r, xg_r);

    // layer 1 recurrence
    k_init_hc<<<(2 * B * H + 255) / 256, 256, 0, stream>>>(h01, c01, h_buf, c_buf);
    dim3 sgrid(H / 64, B / 4, 2);
    for (int s = 0; s < T; ++s) {
        float* hin = h_buf + (s & 1) * 65536;
        float* hout = h_buf + ((s + 1) & 1) * 65536;
        k_lstm_step<<<sgrid, 256, 0, stream>>>(xg_f, xg_r, wt_l1f, wt_l1r, hin, hout,
                                               c_buf, o1, s);
    }

    // layer 2 xg (reuse xg buffers)
    k_gemm_xg<<<ggrid, 256, 0, stream>>>(o1, D2H, l2_Wih_f, l2_b_f, xg_f);
    k_gemm_xg<<<ggrid, 256, 0, stream>>>(o1, D2H, l2_Wih_r, l2_b_r, xg_r);

    // layer 2 recurrence
    k_init_hc<<<(2 * B * H + 255) / 256, 256, 0, stream>>>(h02, c02, h_buf, c_buf);
    for (int s = 0; s < T; ++s) {
        float* hin = h_buf + (s & 1) * 65536;
        float* hout = h_buf + ((s + 1) & 1) * 65536;
        k_lstm_step<<<sgrid, 256, 0, stream>>>(xg_f, xg_r, wt_l2f, wt_l2r, hin, hout,
                                               c_buf, o2, s);
    }

    // gt head
    k_gt<<<(B * T) / 4, 256, 0, stream>>>(o1, gtW, gtb, gt);

    // gated scan -> hs2
    k_scan<<<2 * B, 256, 0, stream>>>(o2, gt, hs2);

    // classifiers + loss + predict
    k_cls<<<(B * T) / 4, 256, 0, stream>>>(o1, hs2, c1W, c1b, c2W, c2b, c3W, c3b, trans,
                                           y_op, y_bd, y_oe, out_pred, out_loss);
}

// Round 2
// 4239.097 us; speedup vs baseline: 1.2659x; 1.2659x over previous
//
#include <hip/hip_runtime.h>
#include <math.h>

#define B 128
#define T 128
#define H 256
#define E 300
#define HD4 1024
#define D2H 512

typedef unsigned short u16;
typedef __attribute__((ext_vector_type(8))) short bf16x8;
typedef __attribute__((ext_vector_type(4))) float f32x4;
typedef __attribute__((address_space(1))) void as1_void;
typedef __attribute__((address_space(3))) void as3_void;

__device__ __forceinline__ float sigm(float x) { return 1.0f / (1.0f + expf(-x)); }
__device__ __forceinline__ float b2f(u16 u) { return __uint_as_float(((unsigned)u) << 16); }
__device__ __forceinline__ u16 f2b(float f) {
    unsigned u = __float_as_uint(f);
    unsigned r = u + 0x7FFFu + ((u >> 16) & 1u);
    return (u16)(r >> 16);
}

// ---------- embedding gather + cast + pad to K=320 ----------
__global__ __launch_bounds__(256) void k_cast_emb(const int* __restrict__ ids,
                                                  const float* __restrict__ tab,
                                                  u16* __restrict__ dst) {
    int idx = blockIdx.x * 256 + threadIdx.x;   // over 16384*40
    int row = idx / 40, kc = (idx - row * 40) * 8;
    if (row >= B * T) return;
    int id = ids[row];
    const float* src = tab + (size_t)id * E + kc;
    bf16x8 v;
#pragma unroll
    for (int j = 0; j < 8; ++j) {
        float fv = 0.0f;
        if (kc + j < E) fv = src[j];
        v[j] = (short)f2b(fv);
    }
    *(bf16x8*)(dst + (size_t)row * 320 + kc) = v;
}

// ---------- generic fp32 [N][Kin] -> bf16 [N][Kpad] (zero-padded) ----------
__global__ __launch_bounds__(256) void k_cast_pad(const float* __restrict__ src,
                                                  u16* __restrict__ dst,
                                                  int N, int Kin, int Kpad) {
    int idx = blockIdx.x * 256 + threadIdx.x;
    int rk = Kpad >> 3;
    int row = idx / rk, kc = (idx - row * rk) * 8;
    if (row >= N) return;
    const float* s = src + (size_t)row * Kin + kc;
    bf16x8 v;
#pragma unroll
    for (int j = 0; j < 8; ++j) {
        float fv = 0.0f;
        if (kc + j < Kin) fv = s[j];
        v[j] = (short)f2b(fv);
    }
    *(bf16x8*)(dst + (size_t)row * Kpad + kc) = v;
}

// ---------- MFMA GEMM: out[(t*B+b)][n] = bf16( A[m]·W[n] + bias[n] ), m=b*T+t ----
// A: bf16 [16384][Kpad], W: bf16 [1024][Kpad]. 128x128 tile, 4 waves 2x2.
__global__ __launch_bounds__(256) void k_gemm_mfma(const u16* __restrict__ A,
                                                   const u16* __restrict__ W,
                                                   const float* __restrict__ bias,
                                                   u16* __restrict__ out, int Kpad) {
    __shared__ u16 aL[128 * 32];
    __shared__ u16 bL[128 * 32];
    const int n0 = blockIdx.x * 128, m0 = blockIdx.y * 128;
    const int tid = threadIdx.x, wid = tid >> 6, l = tid & 63;
    const int wm = wid >> 1, wn = wid & 1;
    const int srow = wid * 16 + (l >> 2);
    const int scol = (l & 3) * 8;

    f32x4 acc[4][4] = {};

    for (int k0 = 0; k0 < Kpad; k0 += 32) {
#pragma unroll
        for (int c = 0; c < 2; ++c) {
            const u16* ga = A + (size_t)(m0 + c * 64 + srow) * Kpad + k0 + scol;
            const u16* gb = W + (size_t)(n0 + c * 64 + srow) * Kpad + k0 + scol;
            __builtin_amdgcn_global_load_lds((const as1_void*)ga,
                                             (as3_void*)&aL[(c * 64 + wid * 16) * 32],
                                             16, 0, 0);
            __builtin_amdgcn_global_load_lds((const as1_void*)gb,
                                             (as3_void*)&bL[(c * 64 + wid * 16) * 32],
                                             16, 0, 0);
        }
        __syncthreads();
        bf16x8 af[4], bf[4];
#pragma unroll
        for (int i = 0; i < 4; ++i)
            af[i] = *(const bf16x8*)&aL[(wm * 64 + i * 16 + (l & 15)) * 32 + (l >> 4) * 8];
#pragma unroll
        for (int j = 0; j < 4; ++j)
            bf[j] = *(const bf16x8*)&bL[(wn * 64 + j * 16 + (l & 15)) * 32 + (l >> 4) * 8];
#pragma unroll
        for (int i = 0; i < 4; ++i)
#pragma unroll
            for (int j = 0; j < 4; ++j)
                acc[i][j] = __builtin_amdgcn_mfma_f32_16x16x32_bf16(af[i], bf[j], acc[i][j], 0, 0, 0);
        __syncthreads();
    }

    float bv[4];
#pragma unroll
    for (int j = 0; j < 4; ++j) bv[j] = bias[n0 + wn * 64 + j * 16 + (l & 15)];
#pragma unroll
    for (int i = 0; i < 4; ++i) {
        int mbase = m0 + wm * 64 + i * 16 + (l >> 4) * 4;
#pragma unroll
        for (int r = 0; r < 4; ++r) {
            int m = mbase + r;
            int bb = m >> 7, tt = m & 127;
            u16* orow = out + (size_t)(tt * B + bb) * HD4 + n0 + wn * 64 + (l & 15);
#pragma unroll
            for (int j = 0; j < 4; ++j) orow[j * 16] = f2b(acc[i][j][r] + bv[j]);
        }
    }
}

// ---------- state init: h bf16, c fp32 ----------
__global__ void k_init_state(const float* __restrict__ h0, const float* __restrict__ c0,
                             u16* __restrict__ h, float* __restrict__ c) {
    int i = blockIdx.x * 256 + threadIdx.x;
    if (i < 2 * B * H) {
        h[i] = f2b(h0[i]);
        c[i] = c0[i];
    }
}

// ---------- one LSTM timestep, MFMA, both dirs via blockIdx.y ----------
// grid (16, 2) blocks, 256 threads. Wave w = gate w, block covers u in [u0,u0+16).
// xg: bf16 [t][b][1024]; Whh: bf16 [1024][256]; h: bf16 [dir][b][256]; o: bf16 [b][t][512]
__global__ __launch_bounds__(256) void k_step_mfma(
    const u16* __restrict__ xg_f, const u16* __restrict__ xg_r,
    const u16* __restrict__ Whf, const u16* __restrict__ Whr,
    const u16* __restrict__ h_in, u16* __restrict__ h_out,
    float* __restrict__ c_state, u16* __restrict__ o, int s) {
    const int d = blockIdx.y;
    const int u0 = blockIdx.x * 16;
    const int t = d ? (T - 1 - s) : s;
    const u16* xg = d ? xg_r : xg_f;
    const u16* W = d ? Whr : Whf;
    const int wid = threadIdx.x >> 6, l = threadIdx.x & 63;
    const int n0 = wid * 256 + u0;

    __shared__ float gbuf[4][128][16];

    // weight fragments for this wave's 16-column n-tile, all K=256 (resident)
    bf16x8 bfrag[8];
    const u16* wbase = W + (size_t)(n0 + (l & 15)) * 256 + (l >> 4) * 8;
#pragma unroll
    for (int ks = 0; ks < 8; ++ks) bfrag[ks] = *(const bf16x8*)(wbase + ks * 32);

    const u16* hbase = h_in + (size_t)d * B * H + (l >> 4) * 8;
#pragma unroll
    for (int mp = 0; mp < 4; ++mp) {
        const u16* ha0 = hbase + (size_t)(mp * 32 + (l & 15)) * 256;
        const u16* ha1 = ha0 + 16 * 256;
        f32x4 acc0{0.f, 0.f, 0.f, 0.f};
        f32x4 acc1{0.f, 0.f, 0.f, 0.f};
#pragma unroll
        for (int ks = 0; ks < 8; ++ks) {
            bf16x8 a0 = *(const bf16x8*)(ha0 + ks * 32);
            bf16x8 a1 = *(const bf16x8*)(ha1 + ks * 32);
            acc0 = __builtin_amdgcn_mfma_f32_16x16x32_bf16(a0, bfrag[ks], acc0, 0, 0, 0);
            acc1 = __builtin_amdgcn_mfma_f32_16x16x32_bf16(a1, bfrag[ks], acc1, 0, 0, 0);
        }
        int brow = mp * 32 + (l >> 4) * 4;
#pragma unroll
        for (int r = 0; r < 4; ++r) {
            gbuf[wid][brow + r][l & 15] = acc0[r];
            gbuf[wid][brow + 16 + r][l & 15] = acc1[r];
        }
    }
    __syncthreads();

#pragma unroll
    for (int i = 0; i < 8; ++i) {
        int cidx = threadIdx.x + 256 * i;     // 0..2047
        int b = cidx >> 4, u = cidx & 15;
        size_t xa = (size_t)(t * B + b) * HD4 + u0 + u;
        float gi = gbuf[0][b][u] + b2f(xg[xa]);
        float gf = gbuf[1][b][u] + b2f(xg[xa + 256]);
        float gg = gbuf[2][b][u] + b2f(xg[xa + 512]);
        float go = gbuf[3][b][u] + b2f(xg[xa + 768]);
        int hidx = (d * B + b) * H + u0 + u;
        float cn = sigm(gf) * c_state[hidx] + sigm(gi) * tanhf(gg);
        float hn = sigm(go) * tanhf(cn);
        c_state[hidx] = cn;
        h_out[hidx] = f2b(hn);
        o[(size_t)(b * T + t) * D2H + d * H + u0 + u] = f2b(hn);
    }
}

// ---------- gt = sigmoid(o1 · gt_W + gt_b) ----------
__global__ __launch_bounds__(256) void k_gt(const u16* __restrict__ o1,
                                            const float* __restrict__ gtW,
                                            const float* __restrict__ gtb,
                                            float* __restrict__ gt) {
    int row = blockIdx.x * 4 + (threadIdx.x >> 6);
    int lane = threadIdx.x & 63;
    const u16* x = o1 + (size_t)row * D2H;
    float p = 0.f;
    for (int j = lane; j < D2H; j += 64) p += b2f(x[j]) * gtW[j];
#pragma unroll
    for (int off = 32; off; off >>= 1) p += __shfl_down(p, off);
    if (lane == 0) gt[row] = sigm(p + gtb[0]);
}

// ---------- gated temporal scan ----------
__global__ void k_scan(const u16* __restrict__ o2, const float* __restrict__ gt,
                       float* __restrict__ hs2) {
    int b = blockIdx.x >> 1;
    int f = ((blockIdx.x & 1) << 8) + threadIdx.x;
    const u16* src = o2 + (size_t)b * T * D2H + f;
    float* dst = hs2 + (size_t)b * T * D2H + f;
    float prev = b2f(src[0]);
    dst[0] = prev;
    for (int t = 1; t < T; ++t) {
        float g = gt[b * T + t];
        prev = g * b2f(src[(size_t)t * D2H]) + (1.0f - g) * prev;
        dst[(size_t)t * D2H] = prev;
    }
}

// ---------- classifiers + softmax + NLL + argmax ----------
__global__ __launch_bounds__(256) void k_cls(
    const u16* __restrict__ o1, const float* __restrict__ hs2,
    const float* __restrict__ c1W, const float* __restrict__ c1b,
    const float* __restrict__ c2W, const float* __restrict__ c2b,
    const float* __restrict__ c3W, const float* __restrict__ c3b,
    const float* __restrict__ trans, const float* __restrict__ y_op,
    const float* __restrict__ y_bd, const float* __restrict__ y_oe,
    float* __restrict__ out_pred, float* __restrict__ out_loss) {
    int row = blockIdx.x * 4 + (threadIdx.x >> 6);
    int lane = threadIdx.x & 63;
    const u16* x1 = o1 + (size_t)row * D2H;
    const float* x2 = hs2 + (size_t)row * D2H;
    float p1[5] = {}, p2[13] = {}, p3[2] = {};
    for (int j = lane; j < D2H; j += 64) {
        float a = b2f(x1[j]), h = x2[j];
#pragma unroll
        for (int c = 0; c < 5; ++c) p1[c] += a * c1W[c * D2H + j];
#pragma unroll
        for (int c = 0; c < 13; ++c) p2[c] += h * c2W[c * D2H + j];
#pragma unroll
        for (int c = 0; c < 2; ++c) p3[c] += a * c3W[c * D2H + j];
    }
#pragma unroll
    for (int c = 0; c < 5; ++c)
#pragma unroll
        for (int off = 32; off; off >>= 1) p1[c] += __shfl_down(p1[c], off);
#pragma unroll
    for (int c = 0; c < 13; ++c)
#pragma unroll
        for (int off = 32; off; off >>= 1) p2[c] += __shfl_down(p2[c], off);
#pragma unroll
    for (int c = 0; c < 2; ++c)
#pragma unroll
        for (int off = 32; off; off >>= 1) p3[c] += __shfl_down(p3[c], off);

    if (lane == 0) {
        float z1[5], z2[13], z3[2];
        float m = -1e30f, s;
        for (int c = 0; c < 5; ++c) { z1[c] = p1[c] + c1b[c]; m = fmaxf(m, z1[c]); }
        s = 0.f;
        for (int c = 0; c < 5; ++c) { z1[c] = expf(z1[c] - m); s += z1[c]; }
        for (int c = 0; c < 5; ++c) z1[c] /= s;
        m = -1e30f;
        for (int c = 0; c < 13; ++c) { z2[c] = p2[c] + c2b[c]; m = fmaxf(m, z2[c]); }
        s = 0.f;
        for (int c = 0; c < 13; ++c) { z2[c] = expf(z2[c] - m); s += z2[c]; }
        for (int c = 0; c < 13; ++c) z2[c] /= s;
        m = fmaxf(p3[0] + c3b[0], p3[1] + c3b[1]);
        z3[0] = expf(p3[0] + c3b[0] - m);
        z3[1] = expf(p3[1] + c3b[1] - m);
        s = z3[0] + z3[1];
        z3[0] /= s; z3[1] /= s;

        float at = 0.f;
        for (int c = 0; c < 5; ++c) at += z1[c] * z1[c];
        at *= 0.5f;

        float lsum = 0.f, best = -1e30f;
        int arg = 0;
        for (int c = 0; c < 13; ++c) {
            float s2v = 0.f;
            for (int j = 0; j < 5; ++j) s2v += z1[j] * trans[j * 13 + c];
            float v = at * s2v + (1.0f - at) * z2[c];
            lsum += y_op[(size_t)row * 13 + c] * logf(v);
            if (v > best) { best = v; arg = c; }
        }
        for (int j = 0; j < 5; ++j) lsum += y_bd[(size_t)row * 5 + j] * logf(z1[j]);
        for (int k = 0; k < 2; ++k) lsum += y_oe[(size_t)row * 2 + k] * logf(z3[k]);
        atomicAdd(out_loss, -lsum * (1.0f / T));
        out_pred[row] = (float)arg;
    }
}

extern "C" void kernel_launch(void* const* d_in, const int* in_sizes, int n_in,
                              void* d_out, int out_size, void* d_ws, size_t ws_size,
                              hipStream_t stream) {
    const int* ids = (const int*)d_in[0];
    const float* y_op = (const float*)d_in[1];
    const float* y_bd = (const float*)d_in[2];
    const float* y_oe = (const float*)d_in[3];
    const float* tab = (const float*)d_in[4];
    const float* trans = (const float*)d_in[5];
    const float* l1_Wih_f = (const float*)d_in[6];
    const float* l1_Whh_f = (const float*)d_in[7];
    const float* l1_b_f = (const float*)d_in[8];
    const float* l1_Wih_r = (const float*)d_in[9];
    const float* l1_Whh_r = (const float*)d_in[10];
    const float* l1_b_r = (const float*)d_in[11];
    const float* l2_Wih_f = (const float*)d_in[12];
    const float* l2_Whh_f = (const float*)d_in[13];
    const float* l2_b_f = (const float*)d_in[14];
    const float* l2_Wih_r = (const float*)d_in[15];
    const float* l2_Whh_r = (const float*)d_in[16];
    const float* l2_b_r = (const float*)d_in[17];
    const float* gtW = (const float*)d_in[18];
    const float* gtb = (const float*)d_in[19];
    const float* c1W = (const float*)d_in[20];
    const float* c1b = (const float*)d_in[21];
    const float* c2W = (const float*)d_in[22];
    const float* c2b = (const float*)d_in[23];
    const float* c3W = (const float*)d_in[24];
    const float* c3b = (const float*)d_in[25];
    const float* h01 = (const float*)d_in[26];
    const float* c01 = (const float*)d_in[27];
    const float* h02 = (const float*)d_in[28];
    const float* c02 = (const float*)d_in[29];

    u16* emb = (u16*)d_ws;                 // 16384*320
    u16* wih1f = emb + 5242880;            // 1024*320
    u16* wih1r = wih1f + 327680;
    u16* wih2f = wih1r + 327680;           // 1024*512
    u16* wih2r = wih2f + 524288;
    u16* whh1f = wih2r + 524288;           // 1024*256
    u16* whh1r = whh1f + 262144;
    u16* whh2f = whh1r + 262144;
    u16* whh2r = whh2f + 262144;
    u16* xgf = whh2r + 262144;             // 16384*1024
    u16* xgr = xgf + 16777216;
    u16* o1 = xgr + 16777216;              // 16384*512
    u16* o2 = o1 + 8388608;
    u16* hbuf = o2 + 8388608;              // 2 * (2*128*256)
    float* c_state = (float*)(hbuf + 131072);  // 2*128*256
    float* gt = c_state + 65536;           // 16384
    float* hs2 = gt + 16384;               // 16384*512

    float* out_pred = (float*)d_out;
    float* out_loss = out_pred + B * T;

    hipMemsetAsync(out_loss, 0, sizeof(float), stream);

    // casts
    k_cast_emb<<<2560, 256, 0, stream>>>(ids, tab, emb);
    k_cast_pad<<<160, 256, 0, stream>>>(l1_Wih_f, wih1f, 1024, 300, 320);
    k_cast_pad<<<160, 256, 0, stream>>>(l1_Wih_r, wih1r, 1024, 300, 320);
    k_cast_pad<<<256, 256, 0, stream>>>(l2_Wih_f, wih2f, 1024, 512, 512);
    k_cast_pad<<<256, 256, 0, stream>>>(l2_Wih_r, wih2r, 1024, 512, 512);
    k_cast_pad<<<128, 256, 0, stream>>>(l1_Whh_f, whh1f, 1024, 256, 256);
    k_cast_pad<<<128, 256, 0, stream>>>(l1_Whh_r, whh1r, 1024, 256, 256);
    k_cast_pad<<<128, 256, 0, stream>>>(l2_Whh_f, whh2f, 1024, 256, 256);
    k_cast_pad<<<128, 256, 0, stream>>>(l2_Whh_r, whh2r, 1024, 256, 256);

    dim3 ggrid(HD4 / 128, (B * T) / 128);

    // layer 1 xg (K=320)
    k_gemm_mfma<<<ggrid, 256, 0, stream>>>(emb, wih1f, l1_b_f, xgf, 320);
    k_gemm_mfma<<<ggrid, 256, 0, stream>>>(emb, wih1r, l1_b_r, xgr, 320);

    // layer 1 recurrence
    k_init_state<<<256, 256, 0, stream>>>(h01, c01, hbuf, c_state);
    dim3 sgrid(16, 2);
    for (int s = 0; s < T; ++s) {
        u16* hin = hbuf + (s & 1) * 65536;
        u16* hout = hbuf + ((s + 1) & 1) * 65536;
        k_step_mfma<<<sgrid, 256, 0, stream>>>(xgf, xgr, whh1f, whh1r, hin, hout,
                                               c_state, o1, s);
    }

    // layer 2 xg (K=512), A = o1 bf16
    k_gemm_mfma<<<ggrid, 256, 0, stream>>>(o1, wih2f, l2_b_f, xgf, 512);
    k_gemm_mfma<<<ggrid, 256, 0, stream>>>(o1, wih2r, l2_b_r, xgr, 512);

    // layer 2 recurrence
    k_init_state<<<256, 256, 0, stream>>>(h02, c02, hbuf, c_state);
    for (int s = 0; s < T; ++s) {
        u16* hin = hbuf + (s & 1) * 65536;
        u16* hout = hbuf + ((s + 1) & 1) * 65536;
        k_step_mfma<<<sgrid, 256, 0, stream>>>(xgf, xgr, whh2f, whh2r, hin, hout,
                                               c_state, o2, s);
    }

    // heads
    k_gt<<<(B * T) / 4, 256, 0, stream>>>(o1, gtW, gtb, gt);
    k_scan<<<2 * B, 256, 0, stream>>>(o2, gt, hs2);
    k_cls<<<(B * T) / 4, 256, 0, stream>>>(o1, hs2, c1W, c1b, c2W, c2b, c3W, c3b, trans,
                                           y_op, y_bd, y_oe, out_pred, out_loss);
}

// Round 3
// 1919.146 us; speedup vs baseline: 2.7962x; 2.2088x over previous
//
#include <hip/hip_runtime.h>
#include <math.h>

#define B 128
#define T 128
#define H 256
#define E 300
#define HD4 1024
#define D2H 512

typedef unsigned short u16;
typedef unsigned long long u64;
typedef __attribute__((ext_vector_type(8))) short bf16x8;
typedef __attribute__((ext_vector_type(4))) float f32x4;
typedef __attribute__((address_space(1))) void as1_void;
typedef __attribute__((address_space(3))) void as3_void;

__device__ __forceinline__ float sigm(float x) { return 1.0f / (1.0f + expf(-x)); }
__device__ __forceinline__ float b2f(u16 u) { return __uint_as_float(((unsigned)u) << 16); }
__device__ __forceinline__ u16 f2b(float f) {
    unsigned u = __float_as_uint(f);
    unsigned r = u + 0x7FFFu + ((u >> 16) & 1u);
    return (u16)(r >> 16);
}

// ---------- embedding gather + cast + pad to K=320 ----------
__global__ __launch_bounds__(256) void k_cast_emb(const int* __restrict__ ids,
                                                  const float* __restrict__ tab,
                                                  u16* __restrict__ dst) {
    int idx = blockIdx.x * 256 + threadIdx.x;   // over 16384*40
    int row = idx / 40, kc = (idx - row * 40) * 8;
    if (row >= B * T) return;
    int id = ids[row];
    const float* src = tab + (size_t)id * E + kc;
    bf16x8 v;
#pragma unroll
    for (int j = 0; j < 8; ++j) {
        float fv = 0.0f;
        if (kc + j < E) fv = src[j];
        v[j] = (short)f2b(fv);
    }
    *(bf16x8*)(dst + (size_t)row * 320 + kc) = v;
}

// ---------- generic fp32 [N][Kin] -> bf16 [N][Kpad] (zero-padded) ----------
__global__ __launch_bounds__(256) void k_cast_pad(const float* __restrict__ src,
                                                  u16* __restrict__ dst,
                                                  int N, int Kin, int Kpad) {
    int idx = blockIdx.x * 256 + threadIdx.x;
    int rk = Kpad >> 3;
    int row = idx / rk, kc = (idx - row * rk) * 8;
    if (row >= N) return;
    const float* s = src + (size_t)row * Kin + kc;
    bf16x8 v;
#pragma unroll
    for (int j = 0; j < 8; ++j) {
        float fv = 0.0f;
        if (kc + j < Kin) fv = s[j];
        v[j] = (short)f2b(fv);
    }
    *(bf16x8*)(dst + (size_t)row * Kpad + kc) = v;
}

// ---------- MFMA GEMM: out[(t*B+b)][n] = bf16( A[m]·W[n] + bias[n] ), m=b*T+t ----
__global__ __launch_bounds__(256) void k_gemm_mfma(const u16* __restrict__ A,
                                                   const u16* __restrict__ W,
                                                   const float* __restrict__ bias,
                                                   u16* __restrict__ out, int Kpad) {
    __shared__ u16 aL[128 * 32];
    __shared__ u16 bL[128 * 32];
    const int n0 = blockIdx.x * 128, m0 = blockIdx.y * 128;
    const int tid = threadIdx.x, wid = tid >> 6, l = tid & 63;
    const int wm = wid >> 1, wn = wid & 1;
    const int srow = wid * 16 + (l >> 2);
    const int scol = (l & 3) * 8;

    f32x4 acc[4][4] = {};

    for (int k0 = 0; k0 < Kpad; k0 += 32) {
#pragma unroll
        for (int c = 0; c < 2; ++c) {
            const u16* ga = A + (size_t)(m0 + c * 64 + srow) * Kpad + k0 + scol;
            const u16* gb = W + (size_t)(n0 + c * 64 + srow) * Kpad + k0 + scol;
            __builtin_amdgcn_global_load_lds((const as1_void*)ga,
                                             (as3_void*)&aL[(c * 64 + wid * 16) * 32],
                                             16, 0, 0);
            __builtin_amdgcn_global_load_lds((const as1_void*)gb,
                                             (as3_void*)&bL[(c * 64 + wid * 16) * 32],
                                             16, 0, 0);
        }
        __syncthreads();
        bf16x8 af[4], bf[4];
#pragma unroll
        for (int i = 0; i < 4; ++i)
            af[i] = *(const bf16x8*)&aL[(wm * 64 + i * 16 + (l & 15)) * 32 + (l >> 4) * 8];
#pragma unroll
        for (int j = 0; j < 4; ++j)
            bf[j] = *(const bf16x8*)&bL[(wn * 64 + j * 16 + (l & 15)) * 32 + (l >> 4) * 8];
#pragma unroll
        for (int i = 0; i < 4; ++i)
#pragma unroll
            for (int j = 0; j < 4; ++j)
                acc[i][j] = __builtin_amdgcn_mfma_f32_16x16x32_bf16(af[i], bf[j], acc[i][j], 0, 0, 0);
        __syncthreads();
    }

    float bv[4];
#pragma unroll
    for (int j = 0; j < 4; ++j) bv[j] = bias[n0 + wn * 64 + j * 16 + (l & 15)];
#pragma unroll
    for (int i = 0; i < 4; ++i) {
        int mbase = m0 + wm * 64 + i * 16 + (l >> 4) * 4;
#pragma unroll
        for (int r = 0; r < 4; ++r) {
            int m = mbase + r;
            int bb = m >> 7, tt = m & 127;
            u16* orow = out + (size_t)(tt * B + bb) * HD4 + n0 + wn * 64 + (l & 15);
#pragma unroll
            for (int j = 0; j < 4; ++j) orow[j * 16] = f2b(acc[i][j][r] + bv[j]);
        }
    }
}

// ---------- persistent bi-LSTM recurrence: ONE launch for all 128 steps ----------
// grid (4 u-chunks, 8 b-chunks, 2 dirs) = 64 blocks, 256 threads.
// Whh register-resident; c in registers; h via ping-pong global buffer with
// per-group (4 block) device-scope barriers.
__global__ __launch_bounds__(256, 1) void k_recur(
    const u16* __restrict__ xg_f, const u16* __restrict__ xg_r,
    const u16* __restrict__ Whf, const u16* __restrict__ Whr,
    const float* __restrict__ h0, const float* __restrict__ c0,
    u16* __restrict__ hbuf, int* __restrict__ cnt, u16* __restrict__ o) {
    const int uc = blockIdx.x;          // 0..3
    const int bc = blockIdx.y;          // 0..7
    const int d = blockIdx.z;           // 0..1
    const int u0 = uc * 64;
    const int b0 = bc * 16;
    const int tid = threadIdx.x, w = tid >> 6, l = tid & 63;
    const u16* xg = d ? xg_r : xg_f;
    const u16* W = d ? Whr : Whf;
    int* mycnt = cnt + (d * 8 + bc) * T;

    __shared__ u16 h_lds[16][264];      // +8 pad kills bank conflicts
    __shared__ float gbuf[4][16][64];

    // resident weight fragments: wave w = gate w, 4 n-tiles x 8 k-slices
    bf16x8 wf[4][8];
#pragma unroll
    for (int j = 0; j < 4; ++j)
#pragma unroll
        for (int ks = 0; ks < 8; ++ks)
            wf[j][ks] = *(const bf16x8*)&W[(size_t)(w * 256 + u0 + j * 16 + (l & 15)) * 256 +
                                           ks * 32 + (l >> 4) * 8];

    // c-state in registers: thread owns (b = tid>>4, u = tu..tu+3)
    const int tb = tid >> 4, tu = (tid & 15) * 4;
    float creg[4];
#pragma unroll
    for (int j = 0; j < 4; ++j)
        creg[j] = c0[(size_t)(d * B + b0 + tb) * H + u0 + tu + j];

    for (int s = 0; s < T; ++s) {
        const int t = d ? (T - 1 - s) : s;

        if (s == 0) {
            const float* hp = h0 + (size_t)(d * B + b0 + (tid >> 4)) * H + (tid & 15) * 16;
            u16* dst = &h_lds[tid >> 4][(tid & 15) * 16];
#pragma unroll
            for (int j = 0; j < 16; ++j) dst[j] = f2b(hp[j]);
        } else {
            if (tid == 0) {
                while (__hip_atomic_load(&mycnt[s - 1], __ATOMIC_ACQUIRE,
                                         __HIP_MEMORY_SCOPE_AGENT) < 4)
                    __builtin_amdgcn_s_sleep(2);
            }
            __syncthreads();
            const u64* src = (const u64*)(hbuf + (size_t)(s & 1) * 2 * B * H +
                                          (size_t)(d * B + b0) * H);
#pragma unroll
            for (int i = 0; i < 4; ++i) {
                int idx = tid + 256 * i;        // 0..1023 ulongs = 8KB
                u64 v = __hip_atomic_load(&src[idx], __ATOMIC_RELAXED,
                                          __HIP_MEMORY_SCOPE_AGENT);
                *(u64*)&h_lds[idx >> 6][(idx & 63) * 4] = v;
            }
        }
        __syncthreads();

        // gates = h · Whh^T for this block's (16 b x 64 u x 4 gates)
        f32x4 acc[4] = {{0.f, 0.f, 0.f, 0.f}, {0.f, 0.f, 0.f, 0.f},
                        {0.f, 0.f, 0.f, 0.f}, {0.f, 0.f, 0.f, 0.f}};
#pragma unroll
        for (int ks = 0; ks < 8; ++ks) {
            bf16x8 a = *(const bf16x8*)&h_lds[l & 15][ks * 32 + (l >> 4) * 8];
#pragma unroll
            for (int j = 0; j < 4; ++j)
                acc[j] = __builtin_amdgcn_mfma_f32_16x16x32_bf16(a, wf[j][ks], acc[j], 0, 0, 0);
        }
#pragma unroll
        for (int j = 0; j < 4; ++j)
#pragma unroll
            for (int r = 0; r < 4; ++r)
                gbuf[w][(l >> 4) * 4 + r][j * 16 + (l & 15)] = acc[j][r];
        __syncthreads();

        // cell update
        const size_t xbase = ((size_t)t * B + b0 + tb) * HD4 + u0 + tu;
        u64 xq0 = *(const u64*)(xg + xbase);
        u64 xq1 = *(const u64*)(xg + xbase + 256);
        u64 xq2 = *(const u64*)(xg + xbase + 512);
        u64 xq3 = *(const u64*)(xg + xbase + 768);
        u64 hv = 0;
#pragma unroll
        for (int j = 0; j < 4; ++j) {
            float gi = gbuf[0][tb][tu + j] + b2f((u16)(xq0 >> (16 * j)));
            float gf = gbuf[1][tb][tu + j] + b2f((u16)(xq1 >> (16 * j)));
            float gg = gbuf[2][tb][tu + j] + b2f((u16)(xq2 >> (16 * j)));
            float go = gbuf[3][tb][tu + j] + b2f((u16)(xq3 >> (16 * j)));
            float cn = sigm(gf) * creg[j] + sigm(gi) * tanhf(gg);
            float hn = sigm(go) * tanhf(cn);
            creg[j] = cn;
            hv |= ((u64)f2b(hn)) << (16 * j);
        }
        // h out -> parity (s+1)&1, device-coherent
        u64* hdst = (u64*)(hbuf + (size_t)((s + 1) & 1) * 2 * B * H) +
                    ((size_t)(d * B + b0 + tb) * H + u0 + tu) / 4;
        __hip_atomic_store(hdst, hv, __ATOMIC_RELAXED, __HIP_MEMORY_SCOPE_AGENT);
        // o output (consumed after kernel boundary)
        *(u64*)&o[((size_t)(b0 + tb) * T + t) * D2H + d * H + u0 + tu] = hv;
        __syncthreads();   // drains all threads' stores (vmcnt 0 before barrier)
        if (tid == 0 && s < T - 1)
            __hip_atomic_fetch_add(&mycnt[s], 1, __ATOMIC_RELEASE, __HIP_MEMORY_SCOPE_AGENT);
    }
}

// ---------- gt = sigmoid(o1 · gt_W + gt_b) ----------
__global__ __launch_bounds__(256) void k_gt(const u16* __restrict__ o1,
                                            const float* __restrict__ gtW,
                                            const float* __restrict__ gtb,
                                            float* __restrict__ gt) {
    int row = blockIdx.x * 4 + (threadIdx.x >> 6);
    int lane = threadIdx.x & 63;
    const u16* x = o1 + (size_t)row * D2H;
    float p = 0.f;
    for (int j = lane; j < D2H; j += 64) p += b2f(x[j]) * gtW[j];
#pragma unroll
    for (int off = 32; off; off >>= 1) p += __shfl_down(p, off);
    if (lane == 0) gt[row] = sigm(p + gtb[0]);
}

// ---------- gated temporal scan ----------
__global__ void k_scan(const u16* __restrict__ o2, const float* __restrict__ gt,
                       float* __restrict__ hs2) {
    int b = blockIdx.x >> 1;
    int f = ((blockIdx.x & 1) << 8) + threadIdx.x;
    const u16* src = o2 + (size_t)b * T * D2H + f;
    float* dst = hs2 + (size_t)b * T * D2H + f;
    float prev = b2f(src[0]);
    dst[0] = prev;
    for (int t = 1; t < T; ++t) {
        float g = gt[b * T + t];
        prev = g * b2f(src[(size_t)t * D2H]) + (1.0f - g) * prev;
        dst[(size_t)t * D2H] = prev;
    }
}

// ---------- classifiers + softmax + NLL + argmax ----------
__global__ __launch_bounds__(256) void k_cls(
    const u16* __restrict__ o1, const float* __restrict__ hs2,
    const float* __restrict__ c1W, const float* __restrict__ c1b,
    const float* __restrict__ c2W, const float* __restrict__ c2b,
    const float* __restrict__ c3W, const float* __restrict__ c3b,
    const float* __restrict__ trans, const float* __restrict__ y_op,
    const float* __restrict__ y_bd, const float* __restrict__ y_oe,
    float* __restrict__ out_pred, float* __restrict__ out_loss) {
    int row = blockIdx.x * 4 + (threadIdx.x >> 6);
    int lane = threadIdx.x & 63;
    const u16* x1 = o1 + (size_t)row * D2H;
    const float* x2 = hs2 + (size_t)row * D2H;
    float p1[5] = {}, p2[13] = {}, p3[2] = {};
    for (int j = lane; j < D2H; j += 64) {
        float a = b2f(x1[j]), h = x2[j];
#pragma unroll
        for (int c = 0; c < 5; ++c) p1[c] += a * c1W[c * D2H + j];
#pragma unroll
        for (int c = 0; c < 13; ++c) p2[c] += h * c2W[c * D2H + j];
#pragma unroll
        for (int c = 0; c < 2; ++c) p3[c] += a * c3W[c * D2H + j];
    }
#pragma unroll
    for (int c = 0; c < 5; ++c)
#pragma unroll
        for (int off = 32; off; off >>= 1) p1[c] += __shfl_down(p1[c], off);
#pragma unroll
    for (int c = 0; c < 13; ++c)
#pragma unroll
        for (int off = 32; off; off >>= 1) p2[c] += __shfl_down(p2[c], off);
#pragma unroll
    for (int c = 0; c < 2; ++c)
#pragma unroll
        for (int off = 32; off; off >>= 1) p3[c] += __shfl_down(p3[c], off);

    if (lane == 0) {
        float z1[5], z2[13], z3[2];
        float m = -1e30f, s;
        for (int c = 0; c < 5; ++c) { z1[c] = p1[c] + c1b[c]; m = fmaxf(m, z1[c]); }
        s = 0.f;
        for (int c = 0; c < 5; ++c) { z1[c] = expf(z1[c] - m); s += z1[c]; }
        for (int c = 0; c < 5; ++c) z1[c] /= s;
        m = -1e30f;
        for (int c = 0; c < 13; ++c) { z2[c] = p2[c] + c2b[c]; m = fmaxf(m, z2[c]); }
        s = 0.f;
        for (int c = 0; c < 13; ++c) { z2[c] = expf(z2[c] - m); s += z2[c]; }
        for (int c = 0; c < 13; ++c) z2[c] /= s;
        m = fmaxf(p3[0] + c3b[0], p3[1] + c3b[1]);
        z3[0] = expf(p3[0] + c3b[0] - m);
        z3[1] = expf(p3[1] + c3b[1] - m);
        s = z3[0] + z3[1];
        z3[0] /= s; z3[1] /= s;

        float at = 0.f;
        for (int c = 0; c < 5; ++c) at += z1[c] * z1[c];
        at *= 0.5f;

        float lsum = 0.f, best = -1e30f;
        int arg = 0;
        for (int c = 0; c < 13; ++c) {
            float s2v = 0.f;
            for (int j = 0; j < 5; ++j) s2v += z1[j] * trans[j * 13 + c];
            float v = at * s2v + (1.0f - at) * z2[c];
            lsum += y_op[(size_t)row * 13 + c] * logf(v);
            if (v > best) { best = v; arg = c; }
        }
        for (int j = 0; j < 5; ++j) lsum += y_bd[(size_t)row * 5 + j] * logf(z1[j]);
        for (int k = 0; k < 2; ++k) lsum += y_oe[(size_t)row * 2 + k] * logf(z3[k]);
        atomicAdd(out_loss, -lsum * (1.0f / T));
        out_pred[row] = (float)arg;
    }
}

extern "C" void kernel_launch(void* const* d_in, const int* in_sizes, int n_in,
                              void* d_out, int out_size, void* d_ws, size_t ws_size,
                              hipStream_t stream) {
    const int* ids = (const int*)d_in[0];
    const float* y_op = (const float*)d_in[1];
    const float* y_bd = (const float*)d_in[2];
    const float* y_oe = (const float*)d_in[3];
    const float* tab = (const float*)d_in[4];
    const float* trans = (const float*)d_in[5];
    const float* l1_Wih_f = (const float*)d_in[6];
    const float* l1_Whh_f = (const float*)d_in[7];
    const float* l1_b_f = (const float*)d_in[8];
    const float* l1_Wih_r = (const float*)d_in[9];
    const float* l1_Whh_r = (const float*)d_in[10];
    const float* l1_b_r = (const float*)d_in[11];
    const float* l2_Wih_f = (const float*)d_in[12];
    const float* l2_Whh_f = (const float*)d_in[13];
    const float* l2_b_f = (const float*)d_in[14];
    const float* l2_Wih_r = (const float*)d_in[15];
    const float* l2_Whh_r = (const float*)d_in[16];
    const float* l2_b_r = (const float*)d_in[17];
    const float* gtW = (const float*)d_in[18];
    const float* gtb = (const float*)d_in[19];
    const float* c1W = (const float*)d_in[20];
    const float* c1b = (const float*)d_in[21];
    const float* c2W = (const float*)d_in[22];
    const float* c2b = (const float*)d_in[23];
    const float* c3W = (const float*)d_in[24];
    const float* c3b = (const float*)d_in[25];
    const float* h01 = (const float*)d_in[26];
    const float* c01 = (const float*)d_in[27];
    const float* h02 = (const float*)d_in[28];
    const float* c02 = (const float*)d_in[29];

    u16* emb = (u16*)d_ws;                 // 16384*320
    u16* wih1f = emb + 5242880;            // 1024*320
    u16* wih1r = wih1f + 327680;
    u16* wih2f = wih1r + 327680;           // 1024*512
    u16* wih2r = wih2f + 524288;
    u16* whh1f = wih2r + 524288;           // 1024*256
    u16* whh1r = whh1f + 262144;
    u16* whh2f = whh1r + 262144;
    u16* whh2r = whh2f + 262144;
    u16* xgf = whh2r + 262144;             // 16384*1024
    u16* xgr = xgf + 16777216;
    u16* o1 = xgr + 16777216;              // 16384*512
    u16* o2 = o1 + 8388608;
    u16* hbuf = o2 + 8388608;              // 2 parity * 2*128*256
    float* gt = (float*)(hbuf + 131072);   // 16384
    float* hs2 = gt + 16384;               // 16384*512
    int* cnt = (int*)(hs2 + 8388608);      // 2 layers * 16 groups * 128 steps

    float* out_pred = (float*)d_out;
    float* out_loss = out_pred + B * T;

    hipMemsetAsync(out_loss, 0, sizeof(float), stream);
    hipMemsetAsync(cnt, 0, 2 * 16 * T * sizeof(int), stream);

    // casts
    k_cast_emb<<<2560, 256, 0, stream>>>(ids, tab, emb);
    k_cast_pad<<<160, 256, 0, stream>>>(l1_Wih_f, wih1f, 1024, 300, 320);
    k_cast_pad<<<160, 256, 0, stream>>>(l1_Wih_r, wih1r, 1024, 300, 320);
    k_cast_pad<<<256, 256, 0, stream>>>(l2_Wih_f, wih2f, 1024, 512, 512);
    k_cast_pad<<<256, 256, 0, stream>>>(l2_Wih_r, wih2r, 1024, 512, 512);
    k_cast_pad<<<128, 256, 0, stream>>>(l1_Whh_f, whh1f, 1024, 256, 256);
    k_cast_pad<<<128, 256, 0, stream>>>(l1_Whh_r, whh1r, 1024, 256, 256);
    k_cast_pad<<<128, 256, 0, stream>>>(l2_Whh_f, whh2f, 1024, 256, 256);
    k_cast_pad<<<128, 256, 0, stream>>>(l2_Whh_r, whh2r, 1024, 256, 256);

    dim3 ggrid(HD4 / 128, (B * T) / 128);
    dim3 rgrid(4, 8, 2);

    // layer 1
    k_gemm_mfma<<<ggrid, 256, 0, stream>>>(emb, wih1f, l1_b_f, xgf, 320);
    k_gemm_mfma<<<ggrid, 256, 0, stream>>>(emb, wih1r, l1_b_r, xgr, 320);
    k_recur<<<rgrid, 256, 0, stream>>>(xgf, xgr, whh1f, whh1r, h01, c01, hbuf, cnt, o1);

    // layer 2
    k_gemm_mfma<<<ggrid, 256, 0, stream>>>(o1, wih2f, l2_b_f, xgf, 512);
    k_gemm_mfma<<<ggrid, 256, 0, stream>>>(o1, wih2r, l2_b_r, xgr, 512);
    k_recur<<<rgrid, 256, 0, stream>>>(xgf, xgr, whh2f, whh2r, h02, c02, hbuf,
                                       cnt + 16 * T, o2);

    // heads
    k_gt<<<(B * T) / 4, 256, 0, stream>>>(o1, gtW, gtb, gt);
    k_scan<<<2 * B, 256, 0, stream>>>(o2, gt, hs2);
    k_cls<<<(B * T) / 4, 256, 0, stream>>>(o1, hs2, c1W, c1b, c2W, c2b, c3W, c3b, trans,
                                           y_op, y_bd, y_oe, out_pred, out_loss);
}